// Round 3
// baseline (454.571 us; speedup 1.0000x reference)
//
#include <hip/hip_runtime.h>

typedef __attribute__((ext_vector_type(8))) short bf16x8;
typedef __attribute__((ext_vector_type(4))) float f32x4;
typedef unsigned short u16;
typedef unsigned int u32;

#define SCALE_ 0.17677669529663687f   // 32^-0.5
#define MFMA(a,b,c) __builtin_amdgcn_mfma_f32_16x16x32_bf16(a,b,c,0,0,0)

__device__ __forceinline__ u16 f2bf(float f){
    u32 u = __float_as_uint(f);
    u = (u + 0x7FFFu + ((u >> 16) & 1u)) >> 16;
    return (u16)u;
}
__device__ __forceinline__ float bf2f(u16 h){ return __uint_as_float(((u32)h) << 16); }
__device__ __forceinline__ u32 pk2(float a, float b){ return (u32)f2bf(a) | ((u32)f2bf(b) << 16); }

// Pack weights to bf16 fragment-friendly rows in workspace.
// Rows 0-255: Wq ; 256-767: Wkv (k then v) ; 768-1023: Wproj ; then 5x256 rpe.
__global__ void prep_kernel(const float* __restrict__ Wkv, const float* __restrict__ Wq,
                            const float* __restrict__ Wproj, const float* __restrict__ rpe,
                            u16* __restrict__ wpk)
{
    int i = blockIdx.x * 256 + threadIdx.x;
    if (i < 262144){
        int row = i >> 8, c = i & 255;
        float v;
        if (row < 256)      v = Wq[(row << 8) | c];
        else if (row < 768) v = Wkv[((row - 256) << 8) | c];
        else                v = Wproj[((row - 768) << 8) | c];
        wpk[i] = f2bf(v);
    } else if (i < 263424){
        wpk[i] = f2bf(rpe[i - 262144]);
    }
}

// Fused MFMA kernel: one block = (n, 4 consecutive t). 256 threads = 4 waves.
__launch_bounds__(256, 2)
__global__ void mhsa_main(const float* __restrict__ x, const float* __restrict__ e,
                          const float* __restrict__ w1, const float* __restrict__ outer,
                          const float* __restrict__ alpha, const float* __restrict__ bproj,
                          const u16* __restrict__ wpk, float* __restrict__ out)
{
    // K-packed layouts: [chunk][col][8] so B-fragments are single b128 reads.
    __shared__ u16 xs [32*32*8];   // x tile  [c>>3][v(32)][c&7]
    __shared__ u16 es2[32*26*8];   // e tile  [c>>3][v(26 pitch)][c&7]
    __shared__ u16 qs [2*32*40];   // q [hl][a(32)][hd, pitch 40]   (rows 25-31 stay 0)
    __shared__ u16 ke [2*4*32*8];  // k+e as B: [hl][hd>>3][col: b0-24,rpe25-29,0][hd&7]
    __shared__ u16 vT [2*32*40];   // v^T as A: [hl][hd][b, pitch 40] (cols 25+ stay 0)
    __shared__ u16 GT [2*4*32*8];  // G^T as B: [hl][b>>3][a][b&7]
    __shared__ u16 opk[32*32*8];   // attn out: [c'>>3][a(32)][c'&7]  (cols 25-31 stay 0)
    __shared__ float biasl[64];    // w1 . e_k  per head-local

    const int tid = threadIdx.x;
    const int w = tid >> 6, lane = tid & 63;
    const int l15 = lane & 15, kg = lane >> 4;
    const int n = blockIdx.x / 30, tq = blockIdx.x % 30;
    const float alpha0 = alpha[0];
    const f32x4 zf = {0.f, 0.f, 0.f, 0.f};

    // zero-init regions whose pads must be 0 / stay 0
    for (int i = tid; i < 2560; i += 256){ qs[i] = 0; vT[i] = 0; }
    for (int i = tid; i < 2048; i += 256){ ke[i] = 0; GT[i] = 0; }
    for (int i = tid; i < 8192; i += 256) opk[i] = 0;
    if (tid < 64) biasl[tid] = 0.f;

    for (int tl = 0; tl < 4; ++tl){
        const int t = tq * 4 + tl;
        const float* xb = x + ((size_t)n * 256 * 120 + t) * 25;
        const float* eb = e + ((size_t)n * 256 * 120 + t) * 25;
        for (int i = tid; i < 8192; i += 256){
            int c = i >> 5, vv = i & 31;
            if (vv < 25){
                xs [((c>>3)*32 + vv)*8 + (c&7)] = f2bf(xb[c*3000 + vv]);
                es2[((c>>3)*26 + vv)*8 + (c&7)] = f2bf(eb[c*3000 + vv]);
            }
        }
        __syncthreads();

        for (int hg = 0; hg < 4; ++hg){
            const int hl = w >> 1;          // head-local for this wave
            const int mt = w & 1;           // tile half
            const int h  = hg * 2 + hl;

            // ===== phase 1: q/k/v = W @ x  (12 m-tiles x 2 n-tiles, K=256) =====
            {
                const u16* Aq = wpk + (((size_t)(hg*64 + w*16 + l15)) << 8) + kg * 8;
                f32x4 cq0 = zf, cq1 = zf, ck0 = zf, ck1 = zf, cv0 = zf, cv1 = zf;
                #pragma unroll
                for (int ks = 0; ks < 8; ++ks){
                    bf16x8 b0 = *(const bf16x8*)&xs[((ks*4+kg)*32 + l15)*8];
                    bf16x8 b1 = *(const bf16x8*)&xs[((ks*4+kg)*32 + 16 + l15)*8];
                    bf16x8 a0 = *(const bf16x8*)(Aq + ks*32);
                    bf16x8 a1 = *(const bf16x8*)(Aq + 65536 + ks*32);
                    bf16x8 a2 = *(const bf16x8*)(Aq + 131072 + ks*32);
                    cq0 = MFMA(a0, b0, cq0); cq1 = MFMA(a0, b1, cq1);
                    ck0 = MFMA(a1, b0, ck0); ck1 = MFMA(a1, b1, ck1);
                    cv0 = MFMA(a2, b0, cv0); cv1 = MFMA(a2, b1, cv1);
                }
                const int hd0 = (w & 1) * 16 + kg * 4;      // C rows = hd0..hd0+3
                const int c0g = h * 32 + hd0;
                #pragma unroll
                for (int nt = 0; nt < 2; ++nt){
                    int node = nt * 16 + l15;
                    if (node < 25){
                        f32x4 q_ = nt ? cq1 : cq0;
                        f32x4 k_ = nt ? ck1 : ck0;
                        f32x4 v_ = nt ? cv1 : cv0;
                        uint2 qp; qp.x = pk2(q_[0], q_[1]); qp.y = pk2(q_[2], q_[3]);
                        *(uint2*)&qs[hl*1280 + node*40 + hd0] = qp;
                        uint2 ep = *(const uint2*)&es2[((c0g>>3)*26 + node)*8 + (c0g&7)];
                        float e0 = bf2f((u16)(ep.x & 0xFFFF)), e1 = bf2f((u16)(ep.x >> 16));
                        float e2 = bf2f((u16)(ep.y & 0xFFFF)), e3 = bf2f((u16)(ep.y >> 16));
                        uint2 kp; kp.x = pk2(k_[0]+e0, k_[1]+e1); kp.y = pk2(k_[2]+e2, k_[3]+e3);
                        *(uint2*)&ke[hl*1024 + ((hd0>>3)*32 + node)*8 + (hd0&7)] = kp;
                        vT[hl*1280 + (hd0+0)*40 + node] = f2bf(v_[0]);
                        vT[hl*1280 + (hd0+1)*40 + node] = f2bf(v_[1]);
                        vT[hl*1280 + (hd0+2)*40 + node] = f2bf(v_[2]);
                        vT[hl*1280 + (hd0+3)*40 + node] = f2bf(v_[3]);
                    }
                }
                // rpe -> ke cols 25-29 (already bf16 in wpk)
                for (int i = tid; i < 320; i += 256){
                    int hl2 = i / 160, rem = i % 160, j = rem >> 5, hd = rem & 31;
                    ke[hl2*1024 + ((hd>>3)*32 + 25 + j)*8 + (hd&7)] =
                        wpk[262144 + j*256 + (hg*2+hl2)*32 + hd];
                }
            }
            __syncthreads();

            // ===== scores: S = q @ (k+e | rpe)  (K=32) =====
            bf16x8 fq  = *(const bf16x8*)&qs[hl*1280 + (mt*16 + l15)*40 + kg*8];
            bf16x8 fk0 = *(const bf16x8*)&ke[hl*1024 + (kg*32 + l15)*8];
            bf16x8 fk1 = *(const bf16x8*)&ke[hl*1024 + (kg*32 + 16 + l15)*8];
            f32x4 s0 = MFMA(fq, fk0, zf);
            f32x4 s1 = MFMA(fq, fk1, zf);
            if ((w & 1) && lane < 25){      // group bias: w1 . e_k[b]
                const float* w1p = w1 + h * 32;
                float sb = 0.f;
                #pragma unroll
                for (int q8 = 0; q8 < 4; ++q8){
                    const u16* ep = &es2[((h*4 + q8)*26 + lane)*8];
                    #pragma unroll
                    for (int u = 0; u < 8; ++u) sb += bf2f(ep[u]) * w1p[q8*8 + u];
                }
                biasl[hl*32 + lane] = sb;
            }
            __syncthreads();

            // ===== softmax in-register (rows spread over 16-lane groups) =====
            {
                const int c0 = l15, c1 = 16 + l15;
                const bool val1 = (c1 < 25);
                const float b0f = biasl[hl*32 + c0];
                const float b1f = biasl[hl*32 + c1];
                float g0[4], g1[4];
                #pragma unroll
                for (int r = 0; r < 4; ++r){
                    const int a = mt*16 + kg*4 + r;
                    float rr0 = __shfl(s1[r], (lane & 48) + 9,  64);
                    float rr1 = __shfl(s1[r], (lane & 48) + 10, 64);
                    float rr2 = __shfl(s1[r], (lane & 48) + 11, 64);
                    float rr3 = __shfl(s1[r], (lane & 48) + 12, 64);
                    float rr4 = __shfl(s1[r], (lane & 48) + 13, 64);
                    int d0 = a - c0; d0 = d0 < 0 ? -d0 : d0; if (d0 > 4) d0 = 4;
                    int d1 = a - c1; d1 = d1 < 0 ? -d1 : d1; if (d1 > 4) d1 = 4;
                    float r0 = d0==0?rr0:d0==1?rr1:d0==2?rr2:d0==3?rr3:rr4;
                    float r1 = d1==0?rr0:d1==1?rr1:d1==2?rr2:d1==3?rr3:rr4;
                    float t0 = (s0[r] + r0 + b0f) * SCALE_;
                    float t1 = (s1[r] + r1 + b1f) * SCALE_;
                    float m = val1 ? fmaxf(t0, t1) : t0;
                    #pragma unroll
                    for (int msk = 1; msk < 16; msk <<= 1)
                        m = fmaxf(m, __shfl_xor(m, msk, 64));
                    float e0v = __expf(t0 - m);
                    float e1v = val1 ? __expf(t1 - m) : 0.f;
                    float sm = e0v + e1v;
                    #pragma unroll
                    for (int msk = 1; msk < 16; msk <<= 1)
                        sm += __shfl_xor(sm, msk, 64);
                    float inv = alpha0 / sm;
                    float o0v = 0.f, o1v = 0.f;
                    if (a < 25){
                        o0v = outer[(h*25 + a)*25 + c0];
                        if (val1) o1v = outer[(h*25 + a)*25 + c1];
                    }
                    g0[r] = e0v * inv + o0v;
                    g1[r] = val1 ? e1v * inv + o1v : 0.f;
                }
                #pragma unroll
                for (int r = 0; r < 4; ++r){
                    const int a = mt*16 + kg*4 + r;
                    GT[hl*1024 + ((c0>>3)*32 + a)*8 + (c0&7)] = f2bf(g0[r]);
                    GT[hl*1024 + ((c1>>3)*32 + a)*8 + (c1&7)] = f2bf(g1[r]);
                }
            }
            __syncthreads();

            // ===== PV: o^T[hd][a] = v^T @ G^T  (K=32, b-padded with zeros) =====
            {
                bf16x8 fv  = *(const bf16x8*)&vT[hl*1280 + (mt*16 + l15)*40 + kg*8];
                bf16x8 fg0 = *(const bf16x8*)&GT[hl*1024 + (kg*32 + l15)*8];
                bf16x8 fg1 = *(const bf16x8*)&GT[hl*1024 + (kg*32 + 16 + l15)*8];
                f32x4 o0 = MFMA(fv, fg0, zf);
                f32x4 o1 = MFMA(fv, fg1, zf);
                const int cp = hg*64 + hl*32 + mt*16 + kg*4;
                uint2 p; p.x = pk2(o0[0], o0[1]); p.y = pk2(o0[2], o0[3]);
                *(uint2*)&opk[((cp>>3)*32 + l15)*8 + (cp&7)] = p;
                if (l15 < 9){
                    uint2 p2; p2.x = pk2(o1[0], o1[1]); p2.y = pk2(o1[2], o1[3]);
                    *(uint2*)&opk[((cp>>3)*32 + 16 + l15)*8 + (cp&7)] = p2;
                }
            }
            __syncthreads();
        } // hg

        // ===== proj: out = Wproj @ o  (K=256) + bias =====
        {
            f32x4 pc[4][2];
            #pragma unroll
            for (int i = 0; i < 4; ++i){ pc[i][0] = zf; pc[i][1] = zf; }
            #pragma unroll
            for (int ks = 0; ks < 8; ++ks){
                bf16x8 pb0 = *(const bf16x8*)&opk[((ks*4+kg)*32 + l15)*8];
                bf16x8 pb1 = *(const bf16x8*)&opk[((ks*4+kg)*32 + 16 + l15)*8];
                #pragma unroll
                for (int i = 0; i < 4; ++i){
                    bf16x8 aw = *(const bf16x8*)(wpk +
                        (((size_t)(768 + w*64 + i*16 + l15)) << 8) + ks*32 + kg*8);
                    pc[i][0] = MFMA(aw, pb0, pc[i][0]);
                    pc[i][1] = MFMA(aw, pb1, pc[i][1]);
                }
            }
            #pragma unroll
            for (int i = 0; i < 4; ++i){
                const int d = w*64 + i*16 + kg*4;
                float bp0 = bproj[d], bp1 = bproj[d+1], bp2 = bproj[d+2], bp3 = bproj[d+3];
                #pragma unroll
                for (int nt = 0; nt < 2; ++nt){
                    int vv = nt*16 + l15;
                    if (vv < 25){
                        float* op = out + ((size_t)(n*256 + d)*120 + t)*25 + vv;
                        f32x4 cc = pc[i][nt];
                        op[0]    = cc[0] + bp0;
                        op[3000] = cc[1] + bp1;
                        op[6000] = cc[2] + bp2;
                        op[9000] = cc[3] + bp3;
                    }
                }
            }
        }
        __syncthreads();
    } // tl
}

extern "C" void kernel_launch(void* const* d_in, const int* in_sizes, int n_in,
                              void* d_out, int out_size, void* d_ws, size_t ws_size,
                              hipStream_t stream) {
    (void)in_sizes; (void)n_in; (void)out_size; (void)ws_size;
    const float* x     = (const float*)d_in[0];
    const float* e     = (const float*)d_in[1];
    const float* Wkv   = (const float*)d_in[2];
    const float* Wq    = (const float*)d_in[3];
    const float* Wproj = (const float*)d_in[4];
    const float* bproj = (const float*)d_in[5];
    const float* rpe   = (const float*)d_in[6];
    const float* w1    = (const float*)d_in[7];
    const float* outer = (const float*)d_in[8];
    const float* alpha = (const float*)d_in[9];
    float* out = (float*)d_out;
    u16* wpk = (u16*)d_ws;

    prep_kernel<<<1029, 256, 0, stream>>>(Wkv, Wq, Wproj, rpe, wpk);
    mhsa_main<<<32 * 30, 256, 0, stream>>>(x, e, w1, outer, alpha, bproj, wpk, out);
}

// Round 5
// 380.738 us; speedup vs baseline: 1.1939x; 1.1939x over previous
//
#include <hip/hip_runtime.h>

typedef __attribute__((ext_vector_type(8))) short bf16x8;
typedef __attribute__((ext_vector_type(4))) float f32x4;
typedef unsigned short u16;
typedef unsigned int u32;

#define SCALE_ 0.17677669529663687f   // 32^-0.5
#define MFMA(a,b,c) __builtin_amdgcn_mfma_f32_16x16x32_bf16(a,b,c,0,0,0)

__device__ __forceinline__ u16 f2bf(float f){
    u32 u = __float_as_uint(f);
    u = (u + 0x7FFFu + ((u >> 16) & 1u)) >> 16;
    return (u16)u;
}
__device__ __forceinline__ float bf2f(u32 h){ return __uint_as_float(h << 16); }
__device__ __forceinline__ u32 pk2(float a, float b){ return (u32)f2bf(a) | ((u32)f2bf(b) << 16); }

// Build an 8-element (K-octet) MFMA fragment from packed C-tiles via shuffles.
// fragment[l15][kg*8+reg] = Ctilepair[row = kg*8+reg][col = l15], where p0 holds
// rows 0-15 and p1 rows 16-31 (regs packed as uint2{(r0,r1),(r2,r3)}).
__device__ __forceinline__ bf16x8 frag8(uint2 p0, uint2 p1, int kg, int l15){
    const int s0 = ((kg & 1) << 5) + l15;
    const int s1 = s0 + 16;
    u32 a0 = (u32)__shfl((int)p0.x, s0, 64);
    u32 a1 = (u32)__shfl((int)p0.y, s0, 64);
    u32 a2 = (u32)__shfl((int)p0.x, s1, 64);
    u32 a3 = (u32)__shfl((int)p0.y, s1, 64);
    u32 b0 = (u32)__shfl((int)p1.x, s0, 64);
    u32 b1 = (u32)__shfl((int)p1.y, s0, 64);
    u32 b2 = (u32)__shfl((int)p1.x, s1, 64);
    u32 b3 = (u32)__shfl((int)p1.y, s1, 64);
    const bool hi = (kg >= 2);
    union { u32 u[4]; bf16x8 v; } r;
    r.u[0] = hi ? b0 : a0; r.u[1] = hi ? b1 : a1;
    r.u[2] = hi ? b2 : a2; r.u[3] = hi ? b3 : a3;
    return r.v;
}

// ws layout (u16 units):
//   [0,      65536)  Wq rows   [d][c] row-major
//   [65536, 131072)  Wk rows
//   [131072,196608)  WvT packed per head: h*8192 + ((c>>3)*32 + hd)*8 + (c&7)
//   [196608,262144)  Wproj rows
//   [262144,263424)  rpe_pk: (j*8 + h)*32 + hd
//   [263424,263680)  w1_pk:  h*32 + hd
__global__ void prep_kernel(const float* __restrict__ Wkv, const float* __restrict__ Wq,
                            const float* __restrict__ Wproj, const float* __restrict__ rpe,
                            const float* __restrict__ w1, u16* __restrict__ wpk)
{
    int i = blockIdx.x * 256 + threadIdx.x;
    if (i < 65536)        wpk[i] = f2bf(Wq[i]);
    else if (i < 131072)  wpk[i] = f2bf(Wkv[i - 65536]);
    else if (i < 196608){
        int j = i - 131072;
        int h = j >> 13;
        int r = j & 8191;
        int coct = r >> 8;
        int hd   = (r >> 3) & 31;
        int clo  = r & 7;
        wpk[i] = f2bf(Wkv[(size_t)(256 + h*32 + hd) * 256 + coct*8 + clo]);
    }
    else if (i < 262144)  wpk[i] = f2bf(Wproj[i - 196608]);
    else if (i < 263424){
        int j = i - 262144;
        int jj = j >> 8, h = (j >> 5) & 7, hd = j & 31;
        wpk[i] = f2bf(rpe[jj*256 + h*32 + hd]);
    }
    else if (i < 263680)  wpk[i] = f2bf(w1[i - 263424]);
}

// One block per (n,t). 4 waves; each wave owns 2 heads end-to-end (no barriers
// inside the head pipeline). 2 block barriers total.
__launch_bounds__(256, 4)
__global__ void mhsa_main(const float* __restrict__ x, const float* __restrict__ e,
                          const float* __restrict__ outer, const float* __restrict__ alpha,
                          const float* __restrict__ bproj, const u16* __restrict__ wpk,
                          float* __restrict__ out)
{
    // xs/es/opk: [c>>3][node pitch 26][c&7] bf16, 13312 B each (+pad for tail reads)
    __shared__ __align__(16) u16 smem[6656*3 + 64];
    u16* xs  = smem;
    u16* es  = smem + 6656;
    u16* opk = smem + 13312;

    const int tid = threadIdx.x;
    const int w = tid >> 6, lane = tid & 63;
    const int l15 = lane & 15, kg = lane >> 4;
    const int n = blockIdx.x / 120, t = blockIdx.x % 120;
    const float alpha0 = alpha[0];
    const f32x4 zf = {0.f, 0.f, 0.f, 0.f};

    // ---- stage x, e (bf16, K-packed) ----
    const float* xb = x + (size_t)n*768000 + t*25;
    const float* eb = e + (size_t)n*768000 + t*25;
    for (int i = tid; i < 6400; i += 256){
        int c = i / 25, v = i - c*25;
        int a16 = ((c>>3)*26 + v)*8 + (c&7);
        xs[a16] = f2bf(xb[c*3000 + v]);
        es[a16] = f2bf(eb[c*3000 + v]);
    }
    __syncthreads();

    for (int hh = 0; hh < 2; ++hh){
        const int h = w*2 + hh;

        // ===== q,k GEMM: M=32(hd) N=32(node) K=256 =====
        f32x4 cq[2][2], ck[2][2];
        #pragma unroll
        for (int i = 0; i < 2; ++i)
            #pragma unroll
            for (int j = 0; j < 2; ++j){ cq[i][j] = zf; ck[i][j] = zf; }
        {
            const u16* wq0 = wpk + (size_t)(h*32 + l15)*256;
            const u16* wk0 = wpk + 65536 + (size_t)(h*32 + l15)*256;
            #pragma unroll
            for (int ks = 0; ks < 8; ++ks){
                bf16x8 b0 = *(const bf16x8*)&xs[((ks*4+kg)*26 + l15)*8];
                bf16x8 b1 = *(const bf16x8*)&xs[((ks*4+kg)*26 + 16 + l15)*8];
                bf16x8 aq0 = *(const bf16x8*)(wq0 + ks*32 + kg*8);
                bf16x8 aq1 = *(const bf16x8*)(wq0 + 4096 + ks*32 + kg*8);
                bf16x8 ak0 = *(const bf16x8*)(wk0 + ks*32 + kg*8);
                bf16x8 ak1 = *(const bf16x8*)(wk0 + 4096 + ks*32 + kg*8);
                cq[0][0]=MFMA(aq0,b0,cq[0][0]); cq[0][1]=MFMA(aq0,b1,cq[0][1]);
                cq[1][0]=MFMA(aq1,b0,cq[1][0]); cq[1][1]=MFMA(aq1,b1,cq[1][1]);
                ck[0][0]=MFMA(ak0,b0,ck[0][0]); ck[0][1]=MFMA(ak0,b1,ck[0][1]);
                ck[1][0]=MFMA(ak1,b0,ck[1][0]); ck[1][1]=MFMA(ak1,b1,ck[1][1]);
            }
        }
        // e-add into ck (KE = k + e_k) and pack q,k C-tiles
        uint2 P_q[2][2], P_k[2][2];
        #pragma unroll
        for (int mt = 0; mt < 2; ++mt)
            #pragma unroll
            for (int nt = 0; nt < 2; ++nt){
                int coct = h*4 + mt*2 + (kg>>1);
                uint2 ev = *(const uint2*)&es[(coct*26 + nt*16 + l15)*8 + (kg&1)*4];
                ck[mt][nt][0] += bf2f(ev.x & 0xFFFFu);
                ck[mt][nt][1] += bf2f(ev.x >> 16);
                ck[mt][nt][2] += bf2f(ev.y & 0xFFFFu);
                ck[mt][nt][3] += bf2f(ev.y >> 16);
                uint2 pq; pq.x = pk2(cq[mt][nt][0], cq[mt][nt][1]);
                pq.y = pk2(cq[mt][nt][2], cq[mt][nt][3]);
                P_q[nt][mt] = pq;
                uint2 pk; pk.x = pk2(ck[mt][nt][0], ck[mt][nt][1]);
                pk.y = pk2(ck[mt][nt][2], ck[mt][nt][3]);
                P_k[nt][mt] = pk;
            }

        // ===== bias[b] = w1_h . e_k[:,b] via broadcast-A MFMA =====
        float bias01[2];
        {
            bf16x8 aw1 = *(const bf16x8*)(wpk + 263424 + h*32 + kg*8);
            bf16x8 be0 = *(const bf16x8*)&es[((h*4+kg)*26 + l15)*8];
            bf16x8 be1 = *(const bf16x8*)&es[((h*4+kg)*26 + 16 + l15)*8];
            f32x4 cb0 = MFMA(aw1, be0, zf);
            f32x4 cb1 = MFMA(aw1, be1, zf);
            bias01[0] = cb0[0]; bias01[1] = cb1[0];
        }

        // ===== v GEMM transposed: C[node][hd] = x^T @ Wv^T =====
        f32x4 cv[2][2];
        #pragma unroll
        for (int i = 0; i < 2; ++i)
            #pragma unroll
            for (int j = 0; j < 2; ++j) cv[i][j] = zf;
        {
            const u16* wvt = wpk + 131072 + h*8192;
            #pragma unroll
            for (int ks = 0; ks < 8; ++ks){
                bf16x8 a0 = *(const bf16x8*)&xs[((ks*4+kg)*26 + l15)*8];
                bf16x8 a1 = *(const bf16x8*)&xs[((ks*4+kg)*26 + 16 + l15)*8];
                bf16x8 bv0 = *(const bf16x8*)&wvt[((ks*4+kg)*32 + l15)*8];
                bf16x8 bv1 = *(const bf16x8*)&wvt[((ks*4+kg)*32 + 16 + l15)*8];
                cv[0][0]=MFMA(a0,bv0,cv[0][0]); cv[0][1]=MFMA(a0,bv1,cv[0][1]);
                cv[1][0]=MFMA(a1,bv0,cv[1][0]); cv[1][1]=MFMA(a1,bv1,cv[1][1]);
            }
        }
        // CRITICAL: zero v rows node>=25 (garbage/NaN from LDS over-read).
        // These become K-columns of the PV A-operand; NaN*0 would poison all
        // output rows (R4 failure mode).
        #pragma unroll
        for (int nt = 0; nt < 2; ++nt)
            #pragma unroll
            for (int r = 0; r < 4; ++r)
                cv[1][nt][r] = (kg*4 + r < 9) ? cv[1][nt][r] : 0.f;

        uint2 P_v[2][2];
        #pragma unroll
        for (int mt = 0; mt < 2; ++mt)
            #pragma unroll
            for (int nt = 0; nt < 2; ++nt){
                uint2 pv; pv.x = pk2(cv[mt][nt][0], cv[mt][nt][1]);
                pv.y = pk2(cv[mt][nt][2], cv[mt][nt][3]);
                P_v[nt][mt] = pv;
            }

        // ===== scores: S^T[b][a] = KE[b][hd] @ q^T[hd][a], K=32 =====
        bf16x8 fq0  = frag8(P_q[0][0], P_q[0][1], kg, l15);
        bf16x8 fq1  = frag8(P_q[1][0], P_q[1][1], kg, l15);
        bf16x8 fke0 = frag8(P_k[0][0], P_k[0][1], kg, l15);
        bf16x8 fke1 = frag8(P_k[1][0], P_k[1][1], kg, l15);
        if (l15 >= 9){   // rows b=25..29: rpe vectors; b=30,31: zero
            if (l15 <= 13)
                fke1 = *(const bf16x8*)(wpk + 262144 + ((l15-9)*8 + h)*32 + kg*8);
            else {
                union { u32 u[4]; bf16x8 v; } z; z.u[0]=z.u[1]=z.u[2]=z.u[3]=0;
                fke1 = z.v;
            }
        }
        f32x4 sc[2][2];
        sc[0][0] = MFMA(fke0, fq0, zf);
        sc[0][1] = MFMA(fke0, fq1, zf);
        sc[1][0] = MFMA(fke1, fq0, zf);
        sc[1][1] = MFMA(fke1, fq1, zf);

        // ===== softmax over b (per column a), fuse alpha*P + outer =====
        uint2 P_G[2][2];
        #pragma unroll
        for (int nt = 0; nt < 2; ++nt){
            const int a = nt*16 + l15;
            f32x4 s0 = sc[0][nt], s1 = sc[1][nt];
            // R[j][a] lives in S^T rows 25+j -> (kg,r): j0:(2,1) j1:(2,2) j2:(2,3) j3:(3,0) j4:(3,1)
            float rr0 = __shfl(s1[1], 32 + l15, 64);
            float rr1 = __shfl(s1[2], 32 + l15, 64);
            float rr2 = __shfl(s1[3], 32 + l15, 64);
            float rr3 = __shfl(s1[0], 48 + l15, 64);
            float rr4 = __shfl(s1[1], 48 + l15, 64);
            float tv[8];
            #pragma unroll
            for (int mt = 0; mt < 2; ++mt)
                #pragma unroll
                for (int r = 0; r < 4; ++r){
                    int b = mt*16 + kg*4 + r;
                    float sval = mt ? s1[r] : s0[r];
                    float bb = __shfl(bias01[mt], (lane & 48) + (b & 15), 64);
                    int d = a - b; d = d < 0 ? -d : d; if (d > 4) d = 4;
                    float rj = d==0?rr0 : d==1?rr1 : d==2?rr2 : d==3?rr3 : rr4;
                    float tt = (sval + rj + bb) * SCALE_;
                    tv[mt*4+r] = (b < 25) ? tt : -1e30f;
                }
            float m = tv[0];
            #pragma unroll
            for (int i = 1; i < 8; ++i) m = fmaxf(m, tv[i]);
            m = fmaxf(m, __shfl_xor(m, 16, 64));
            m = fmaxf(m, __shfl_xor(m, 32, 64));
            float ex[8], sm = 0.f;
            #pragma unroll
            for (int i = 0; i < 8; ++i){ ex[i] = __expf(tv[i] - m); sm += ex[i]; }
            sm += __shfl_xor(sm, 16, 64);
            sm += __shfl_xor(sm, 32, 64);
            const float inv = alpha0 / sm;
            float g[8];
            #pragma unroll
            for (int mt = 0; mt < 2; ++mt)
                #pragma unroll
                for (int r = 0; r < 4; ++r){
                    int b = mt*16 + kg*4 + r;
                    float ov = (a < 25 && b < 25) ? outer[((size_t)h*25 + a)*25 + b] : 0.f;
                    g[mt*4+r] = (b < 25) ? ex[mt*4+r]*inv + ov : 0.f;
                }
            uint2 pg0; pg0.x = pk2(g[0], g[1]); pg0.y = pk2(g[2], g[3]);
            uint2 pg1; pg1.x = pk2(g[4], g[5]); pg1.y = pk2(g[6], g[7]);
            P_G[nt][0] = pg0; P_G[nt][1] = pg1;
        }

        // ===== PV: C[hd][a] = v^T[hd][b] @ G^T[b][a], K=32 =====
        {
            bf16x8 fv0 = frag8(P_v[0][0], P_v[0][1], kg, l15);
            bf16x8 fv1 = frag8(P_v[1][0], P_v[1][1], kg, l15);
            bf16x8 fg0 = frag8(P_G[0][0], P_G[0][1], kg, l15);
            bf16x8 fg1 = frag8(P_G[1][0], P_G[1][1], kg, l15);
            f32x4 o[2][2];
            o[0][0] = MFMA(fv0, fg0, zf); o[0][1] = MFMA(fv0, fg1, zf);
            o[1][0] = MFMA(fv1, fg0, zf); o[1][1] = MFMA(fv1, fg1, zf);
            #pragma unroll
            for (int mt = 0; mt < 2; ++mt)
                #pragma unroll
                for (int nt = 0; nt < 2; ++nt){
                    int a = nt*16 + l15;
                    if (a < 25){
                        int coct = h*4 + mt*2 + (kg>>1);
                        u32* dst = (u32*)&opk[(coct*26 + a)*8 + (kg&1)*4];
                        dst[0] = pk2(o[mt][nt][0], o[mt][nt][1]);
                        dst[1] = pk2(o[mt][nt][2], o[mt][nt][3]);
                    }
                }
        }
    } // hh
    __syncthreads();

    // ===== proj: out = Wproj @ o + bproj, K=256, cooperative =====
    {
        f32x4 pc[4][2];
        #pragma unroll
        for (int i = 0; i < 4; ++i){ pc[i][0] = zf; pc[i][1] = zf; }
        #pragma unroll
        for (int ks = 0; ks < 8; ++ks){
            bf16x8 pb0 = *(const bf16x8*)&opk[((ks*4+kg)*26 + l15)*8];
            bf16x8 pb1 = *(const bf16x8*)&opk[((ks*4+kg)*26 + 16 + l15)*8];
            #pragma unroll
            for (int i = 0; i < 4; ++i){
                bf16x8 aw = *(const bf16x8*)(wpk + 196608 +
                                (size_t)(w*64 + i*16 + l15)*256 + ks*32 + kg*8);
                pc[i][0] = MFMA(aw, pb0, pc[i][0]);
                pc[i][1] = MFMA(aw, pb1, pc[i][1]);
            }
        }
        #pragma unroll
        for (int i = 0; i < 4; ++i){
            const int d = w*64 + i*16 + kg*4;
            float b0 = bproj[d], b1 = bproj[d+1], b2 = bproj[d+2], b3 = bproj[d+3];
            #pragma unroll
            for (int nt = 0; nt < 2; ++nt){
                int v = nt*16 + l15;
                if (v < 25){
                    float* op = out + (size_t)n*768000 + (size_t)d*3000 + t*25 + v;
                    op[0]    = pc[i][nt][0] + b0;
                    op[3000] = pc[i][nt][1] + b1;
                    op[6000] = pc[i][nt][2] + b2;
                    op[9000] = pc[i][nt][3] + b3;
                }
            }
        }
    }
}

extern "C" void kernel_launch(void* const* d_in, const int* in_sizes, int n_in,
                              void* d_out, int out_size, void* d_ws, size_t ws_size,
                              hipStream_t stream) {
    (void)in_sizes; (void)n_in; (void)out_size; (void)ws_size;
    const float* x     = (const float*)d_in[0];
    const float* e     = (const float*)d_in[1];
    const float* Wkv   = (const float*)d_in[2];
    const float* Wq    = (const float*)d_in[3];
    const float* Wproj = (const float*)d_in[4];
    const float* bproj = (const float*)d_in[5];
    const float* rpe   = (const float*)d_in[6];
    const float* w1    = (const float*)d_in[7];
    const float* outer = (const float*)d_in[8];
    const float* alpha = (const float*)d_in[9];
    float* out = (float*)d_out;
    u16* wpk = (u16*)d_ws;

    prep_kernel<<<1030, 256, 0, stream>>>(Wkv, Wq, Wproj, rpe, w1, wpk);
    mhsa_main<<<32*120, 256, 0, stream>>>(x, e, outer, alpha, bproj, wpk, out);
}